// Round 6
// baseline (2130.509 us; speedup 1.0000x reference)
//
#include <hip/hip_runtime.h>

#define BB 64
#define SS 1024
#define HH 512

typedef short short8 __attribute__((ext_vector_type(8)));
typedef float f32x4 __attribute__((ext_vector_type(4)));
typedef _Float16 h2 __attribute__((ext_vector_type(2)));

__device__ inline unsigned short f2bf(float f) {
  unsigned int u = __builtin_bit_cast(unsigned int, f);
  u += 0x7fffu + ((u >> 16) & 1u);   // round-to-nearest-even
  return (unsigned short)(u >> 16);
}

__device__ inline unsigned int pack_h2(float a, float b) {
  unsigned short ua = __builtin_bit_cast(unsigned short, (_Float16)a);
  unsigned short ub = __builtin_bit_cast(unsigned short, (_Float16)b);
  return (unsigned int)ua | ((unsigned int)ub << 16);
}

__device__ inline float dot2a(unsigned int w, unsigned int h, float acc) {
#if __has_builtin(__builtin_amdgcn_fdot2)
  return __builtin_amdgcn_fdot2(__builtin_bit_cast(h2, w),
                                __builtin_bit_cast(h2, h), acc, false);
#else
  h2 a = __builtin_bit_cast(h2, w);
  h2 b = __builtin_bit_cast(h2, h);
  return acc + (float)a[0] * (float)b[0] + (float)a[1] * (float)b[1];
#endif
}

// ---------------------------------------------------------------------------
// Phase 1: xt[m, n] = sum_k x[m,k] * W_ih[n,k] + b_ih[n],  m = b*S + s
// bf16 MFMA 16x16x32, BM=BN=64, BK=32, 256 threads (4 waves, 2x2 wave grid).
// Writes fp32 into d_out[0 : B*S*H]; phase 2 overwrites in place.
// ---------------------------------------------------------------------------
__global__ __launch_bounds__(256) void xt_gemm(
    const float* __restrict__ x, const float* __restrict__ Wih,
    const float* __restrict__ bih, float* __restrict__ out) {
  __shared__ unsigned short As[64][56];
  __shared__ unsigned short Bs[64][56];

  const int bn = blockIdx.x;  // 0..7
  const int bm = blockIdx.y;  // 0..1023
  const int t = threadIdx.x;
  const int wave = t >> 6, lane = t & 63;
  const int wm = wave >> 1, wn = wave & 1;
  const int m_base = bm * 64, n_base = bn * 64;
  const int sr = t >> 2;        // staging row 0..63
  const int sc = (t & 3) * 8;   // staging col chunk 0,8,16,24

  f32x4 acc[2][2] = {};

  for (int k0 = 0; k0 < 512; k0 += 32) {
    __syncthreads();
    {
      const float* p = x + (size_t)(m_base + sr) * 512 + k0 + sc;
      float4 v0 = *(const float4*)p;
      float4 v1 = *(const float4*)(p + 4);
      short8 sa;
      sa[0] = (short)f2bf(v0.x); sa[1] = (short)f2bf(v0.y);
      sa[2] = (short)f2bf(v0.z); sa[3] = (short)f2bf(v0.w);
      sa[4] = (short)f2bf(v1.x); sa[5] = (short)f2bf(v1.y);
      sa[6] = (short)f2bf(v1.z); sa[7] = (short)f2bf(v1.w);
      *(short8*)&As[sr][sc] = sa;

      const float* q = Wih + (size_t)(n_base + sr) * 512 + k0 + sc;
      float4 w0 = *(const float4*)q;
      float4 w1 = *(const float4*)(q + 4);
      short8 sb;
      sb[0] = (short)f2bf(w0.x); sb[1] = (short)f2bf(w0.y);
      sb[2] = (short)f2bf(w0.z); sb[3] = (short)f2bf(w0.w);
      sb[4] = (short)f2bf(w1.x); sb[5] = (short)f2bf(w1.y);
      sb[6] = (short)f2bf(w1.z); sb[7] = (short)f2bf(w1.w);
      *(short8*)&Bs[sr][sc] = sb;
    }
    __syncthreads();

    const int kq = (lane >> 4) * 8;  // k-chunk within BK
    short8 a0 = *(const short8*)&As[wm * 32 + (lane & 15)][kq];
    short8 a1 = *(const short8*)&As[wm * 32 + 16 + (lane & 15)][kq];
    short8 b0 = *(const short8*)&Bs[wn * 32 + (lane & 15)][kq];
    short8 b1 = *(const short8*)&Bs[wn * 32 + 16 + (lane & 15)][kq];
    acc[0][0] = __builtin_amdgcn_mfma_f32_16x16x32_bf16(a0, b0, acc[0][0], 0, 0, 0);
    acc[0][1] = __builtin_amdgcn_mfma_f32_16x16x32_bf16(a0, b1, acc[0][1], 0, 0, 0);
    acc[1][0] = __builtin_amdgcn_mfma_f32_16x16x32_bf16(a1, b0, acc[1][0], 0, 0, 0);
    acc[1][1] = __builtin_amdgcn_mfma_f32_16x16x32_bf16(a1, b1, acc[1][1], 0, 0, 0);
  }

  // C/D layout (m89-verified): col = lane&15 (N), row = (lane>>4)*4 + j (M)
#pragma unroll
  for (int ni = 0; ni < 2; ++ni) {
    const int gcol = n_base + wn * 32 + ni * 16 + (lane & 15);
    const float bv = bih[gcol];
#pragma unroll
    for (int mi = 0; mi < 2; ++mi) {
#pragma unroll
      for (int j = 0; j < 4; ++j) {
        const int grow = m_base + wm * 32 + mi * 16 + (lane >> 4) * 4 + j;
        out[(size_t)grow * 512 + gcol] = acc[mi][ni][j] + bv;
      }
    }
  }
}

// ---------------------------------------------------------------------------
// Phase 2: per-batch sequential scan, one WG (512 threads, 8 waves) per chain.
// Full W_hh residency, bypassing the 128-VGPR allocator ceiling with AGPRs:
//   rows i=0..3 -> 128 dwords/thread in AGPRs (explicit v_accvgpr_write/read)
//   rows i=4..5 ->  64 dwords/thread in VGPRs (asm-pinned; fits under 128)
//   rows i=6..7 ->  64 dwords/thread in LDS   (128 KB)
// Per wave: 128 arch-VGPR + 128 AGPR = 256 <= unified-file cap at 2 waves/EU.
// Thread t: kg = t>>6 (k-span 64, wave-uniform), hg = t&63; rows h = hg+64*i.
// ---------------------------------------------------------------------------
__global__ __launch_bounds__(512, 1) void rnn_scan(
    const float* __restrict__ Whh, const float* __restrict__ bhh,
    float* __restrict__ out, float* __restrict__ last) {
  __shared__ uint4 wlds[16 * 512];        // 128 KB: W rows hg+384, hg+448
  __shared__ float part[8 * 512];         // 16 KB partials
  __shared__ unsigned short hbuf[512];    // 1 KB h state (f16)

  const int b = blockIdx.x;
  const int t = threadIdx.x;
  const int kg = t >> 6;        // 0..7, wave-uniform
  const int hg = t & 63;
  const int k0 = kg * 64;

  // --- rows i=0..3 into AGPRs (128 dwords, storage class forced by asm) ---
  unsigned int wag[4][32];
#pragma unroll
  for (int i = 0; i < 4; ++i) {
    const float* wr = Whh + (size_t)(hg + 64 * i) * 512 + k0;
#pragma unroll
    for (int c4 = 0; c4 < 16; ++c4) {
      float4 f = ((const float4*)wr)[c4];
      unsigned int lo = pack_h2(f.x, f.y);
      unsigned int hi = pack_h2(f.z, f.w);
      asm volatile("v_accvgpr_write_b32 %0, %1" : "=a"(wag[i][2 * c4])     : "v"(lo));
      asm volatile("v_accvgpr_write_b32 %0, %1" : "=a"(wag[i][2 * c4 + 1]) : "v"(hi));
    }
  }

  // --- rows i=4..5 into VGPRs (64 dwords; pinned vs remat) ---
  unsigned int wreg[2][32];
#pragma unroll
  for (int i = 0; i < 2; ++i) {
    const float* wr = Whh + (size_t)(hg + 64 * (4 + i)) * 512 + k0;
#pragma unroll
    for (int c4 = 0; c4 < 16; ++c4) {
      float4 f = ((const float4*)wr)[c4];
      wreg[i][c4 * 2]     = pack_h2(f.x, f.y);
      wreg[i][c4 * 2 + 1] = pack_h2(f.z, f.w);
    }
  }
#pragma unroll
  for (int i = 0; i < 2; ++i)
#pragma unroll
    for (int d = 0; d < 32; ++d) asm volatile("" : "+v"(wreg[i][d]));

  // --- rows i=6..7 into LDS ---
#pragma unroll
  for (int i = 6; i < 8; ++i) {
    const float* wr = Whh + (size_t)(hg + 64 * i) * 512 + k0;
#pragma unroll
    for (int c = 0; c < 8; ++c) {
      float4 f0 = ((const float4*)wr)[c * 2];
      float4 f1 = ((const float4*)wr)[c * 2 + 1];
      uint4 v;
      v.x = pack_h2(f0.x, f0.y); v.y = pack_h2(f0.z, f0.w);
      v.z = pack_h2(f1.x, f1.y); v.w = pack_h2(f1.z, f1.w);
      wlds[((i - 6) * 8 + c) * 512 + t] = v;
    }
  }
  if (t < 256) ((unsigned int*)hbuf)[t] = 0;  // h_0 = 0

  float* xt_row = out + (size_t)b * SS * HH;
  float xt_cur = xt_row[t];
  const float bh = bhh[t];
  const uint4* h4 = (const uint4*)hbuf + kg * 8;
  __syncthreads();

  // AGPR-resident dot2: read back then fdot2 (read asm is pure -> schedulable)
#define DOT_A(i, idx, hcomp)                                             \
  {                                                                      \
    unsigned int _tmp;                                                   \
    asm("v_accvgpr_read_b32 %0, %1" : "=v"(_tmp) : "a"(wag[i][idx]));    \
    a[i] = dot2a(_tmp, hcomp, a[i]);                                     \
  }

  for (int step = 0; step < SS; ++step) {
    // prefetch next xt (consumed next iteration; hides under dot phase)
    float xt_next = 0.f;
    if (step + 1 < SS) xt_next = xt_row[(size_t)(step + 1) * HH + t];

    // --- dot phase: a[i] = sum over k-span of W[hg+64i][k] * h[k] ---
    float a[8] = {0.f, 0.f, 0.f, 0.f, 0.f, 0.f, 0.f, 0.f};
#pragma unroll
    for (int c = 0; c < 8; ++c) {
      uint4 hv = h4[c];                      // broadcast (wave-uniform addr)
      uint4 w6 = wlds[c * 512 + t];          // conflict-free b128
      uint4 w7 = wlds[(8 + c) * 512 + t];
      DOT_A(0, 4 * c + 0, hv.x); DOT_A(0, 4 * c + 1, hv.y);
      DOT_A(0, 4 * c + 2, hv.z); DOT_A(0, 4 * c + 3, hv.w);
      DOT_A(1, 4 * c + 0, hv.x); DOT_A(1, 4 * c + 1, hv.y);
      DOT_A(1, 4 * c + 2, hv.z); DOT_A(1, 4 * c + 3, hv.w);
      DOT_A(2, 4 * c + 0, hv.x); DOT_A(2, 4 * c + 1, hv.y);
      DOT_A(2, 4 * c + 2, hv.z); DOT_A(2, 4 * c + 3, hv.w);
      DOT_A(3, 4 * c + 0, hv.x); DOT_A(3, 4 * c + 1, hv.y);
      DOT_A(3, 4 * c + 2, hv.z); DOT_A(3, 4 * c + 3, hv.w);
      a[4] = dot2a(wreg[0][4 * c + 0], hv.x, a[4]);
      a[4] = dot2a(wreg[0][4 * c + 1], hv.y, a[4]);
      a[4] = dot2a(wreg[0][4 * c + 2], hv.z, a[4]);
      a[4] = dot2a(wreg[0][4 * c + 3], hv.w, a[4]);
      a[5] = dot2a(wreg[1][4 * c + 0], hv.x, a[5]);
      a[5] = dot2a(wreg[1][4 * c + 1], hv.y, a[5]);
      a[5] = dot2a(wreg[1][4 * c + 2], hv.z, a[5]);
      a[5] = dot2a(wreg[1][4 * c + 3], hv.w, a[5]);
      a[6] = dot2a(w6.x, hv.x, a[6]);
      a[6] = dot2a(w6.y, hv.y, a[6]);
      a[6] = dot2a(w6.z, hv.z, a[6]);
      a[6] = dot2a(w6.w, hv.w, a[6]);
      a[7] = dot2a(w7.x, hv.x, a[7]);
      a[7] = dot2a(w7.y, hv.y, a[7]);
      a[7] = dot2a(w7.z, hv.z, a[7]);
      a[7] = dot2a(w7.w, hv.w, a[7]);
    }
    // partial store: within a wave lanes write consecutive dwords
#pragma unroll
    for (int i = 0; i < 8; ++i) part[kg * 512 + hg + 64 * i] = a[i];
    __syncthreads();

    // --- finalize: all 512 threads, h = t ---
    float y = xt_cur + bh;
#pragma unroll
    for (int g = 0; g < 8; ++g) y += part[g * 512 + t];
    float ht = tanhf(y);
    xt_row[(size_t)step * HH + t] = ht;  // overwrite xt with output h
    hbuf[t] = __builtin_bit_cast(unsigned short, (_Float16)ht);
    xt_cur = xt_next;
    __syncthreads();
  }

  // last = h_{S-1}: re-read the fp32 value just stored (L1/L2-hot)
  last[(size_t)b * HH + t] = xt_row[(size_t)(SS - 1) * HH + t];
#undef DOT_A
}

extern "C" void kernel_launch(void* const* d_in, const int* in_sizes, int n_in,
                              void* d_out, int out_size, void* d_ws, size_t ws_size,
                              hipStream_t stream) {
  (void)in_sizes; (void)n_in; (void)d_ws; (void)ws_size; (void)out_size;
  const float* x   = (const float*)d_in[0];
  const float* Wih = (const float*)d_in[1];
  const float* bih = (const float*)d_in[2];
  const float* Whh = (const float*)d_in[3];
  const float* bhh = (const float*)d_in[4];
  float* out  = (float*)d_out;
  float* last = out + (size_t)BB * SS * HH;

  // Phase 1: input projection for all timesteps -> d_out (in-place xt buffer)
  xt_gemm<<<dim3(8, 1024), 256, 0, stream>>>(x, Wih, bih, out);

  // Phase 2: 64 sync-free per-batch chains, 145 KB static LDS each
  rnn_scan<<<64, 512, 0, stream>>>(Whh, bhh, out, last);
}

// Round 7
// 1751.807 us; speedup vs baseline: 1.2162x; 1.2162x over previous
//
#include <hip/hip_runtime.h>

#define BB 64
#define SS 1024
#define HH 512

typedef short short8 __attribute__((ext_vector_type(8)));
typedef float f32x4 __attribute__((ext_vector_type(4)));
typedef _Float16 h2 __attribute__((ext_vector_type(2)));

__device__ inline unsigned short f2bf(float f) {
  unsigned int u = __builtin_bit_cast(unsigned int, f);
  u += 0x7fffu + ((u >> 16) & 1u);   // round-to-nearest-even
  return (unsigned short)(u >> 16);
}

__device__ inline unsigned int pack_h2(float a, float b) {
  unsigned short ua = __builtin_bit_cast(unsigned short, (_Float16)a);
  unsigned short ub = __builtin_bit_cast(unsigned short, (_Float16)b);
  return (unsigned int)ua | ((unsigned int)ub << 16);
}

__device__ inline float dot2a(unsigned int w, unsigned int h, float acc) {
#if __has_builtin(__builtin_amdgcn_fdot2)
  return __builtin_amdgcn_fdot2(__builtin_bit_cast(h2, w),
                                __builtin_bit_cast(h2, h), acc, false);
#else
  h2 a = __builtin_bit_cast(h2, w);
  h2 b = __builtin_bit_cast(h2, h);
  return acc + (float)a[0] * (float)b[0] + (float)a[1] * (float)b[1];
#endif
}

// ---------------------------------------------------------------------------
// Phase 1: xt[m, n] = sum_k x[m,k] * W_ih[n,k] + b_ih[n],  m = b*S + s
// bf16 MFMA 16x16x32, BM=BN=64, BK=32, 256 threads (4 waves, 2x2 wave grid).
// Writes fp32 into d_out[0 : B*S*H]; phase 2 overwrites in place.
// ---------------------------------------------------------------------------
__global__ __launch_bounds__(256) void xt_gemm(
    const float* __restrict__ x, const float* __restrict__ Wih,
    const float* __restrict__ bih, float* __restrict__ out) {
  __shared__ unsigned short As[64][56];
  __shared__ unsigned short Bs[64][56];

  const int bn = blockIdx.x;  // 0..7
  const int bm = blockIdx.y;  // 0..1023
  const int t = threadIdx.x;
  const int wave = t >> 6, lane = t & 63;
  const int wm = wave >> 1, wn = wave & 1;
  const int m_base = bm * 64, n_base = bn * 64;
  const int sr = t >> 2;        // staging row 0..63
  const int sc = (t & 3) * 8;   // staging col chunk 0,8,16,24

  f32x4 acc[2][2] = {};

  for (int k0 = 0; k0 < 512; k0 += 32) {
    __syncthreads();
    {
      const float* p = x + (size_t)(m_base + sr) * 512 + k0 + sc;
      float4 v0 = *(const float4*)p;
      float4 v1 = *(const float4*)(p + 4);
      short8 sa;
      sa[0] = (short)f2bf(v0.x); sa[1] = (short)f2bf(v0.y);
      sa[2] = (short)f2bf(v0.z); sa[3] = (short)f2bf(v0.w);
      sa[4] = (short)f2bf(v1.x); sa[5] = (short)f2bf(v1.y);
      sa[6] = (short)f2bf(v1.z); sa[7] = (short)f2bf(v1.w);
      *(short8*)&As[sr][sc] = sa;

      const float* q = Wih + (size_t)(n_base + sr) * 512 + k0 + sc;
      float4 w0 = *(const float4*)q;
      float4 w1 = *(const float4*)(q + 4);
      short8 sb;
      sb[0] = (short)f2bf(w0.x); sb[1] = (short)f2bf(w0.y);
      sb[2] = (short)f2bf(w0.z); sb[3] = (short)f2bf(w0.w);
      sb[4] = (short)f2bf(w1.x); sb[5] = (short)f2bf(w1.y);
      sb[6] = (short)f2bf(w1.z); sb[7] = (short)f2bf(w1.w);
      *(short8*)&Bs[sr][sc] = sb;
    }
    __syncthreads();

    const int kq = (lane >> 4) * 8;  // k-chunk within BK
    short8 a0 = *(const short8*)&As[wm * 32 + (lane & 15)][kq];
    short8 a1 = *(const short8*)&As[wm * 32 + 16 + (lane & 15)][kq];
    short8 b0 = *(const short8*)&Bs[wn * 32 + (lane & 15)][kq];
    short8 b1 = *(const short8*)&Bs[wn * 32 + 16 + (lane & 15)][kq];
    acc[0][0] = __builtin_amdgcn_mfma_f32_16x16x32_bf16(a0, b0, acc[0][0], 0, 0, 0);
    acc[0][1] = __builtin_amdgcn_mfma_f32_16x16x32_bf16(a0, b1, acc[0][1], 0, 0, 0);
    acc[1][0] = __builtin_amdgcn_mfma_f32_16x16x32_bf16(a1, b0, acc[1][0], 0, 0, 0);
    acc[1][1] = __builtin_amdgcn_mfma_f32_16x16x32_bf16(a1, b1, acc[1][1], 0, 0, 0);
  }

  // C/D layout (m89-verified): col = lane&15 (N), row = (lane>>4)*4 + j (M)
#pragma unroll
  for (int ni = 0; ni < 2; ++ni) {
    const int gcol = n_base + wn * 32 + ni * 16 + (lane & 15);
    const float bv = bih[gcol];
#pragma unroll
    for (int mi = 0; mi < 2; ++mi) {
#pragma unroll
      for (int j = 0; j < 4; ++j) {
        const int grow = m_base + wm * 32 + mi * 16 + (lane >> 4) * 4 + j;
        out[(size_t)grow * 512 + gcol] = acc[mi][ni][j] + bv;
      }
    }
  }
}

// ---------------------------------------------------------------------------
// Phase 2: per-batch sequential scan, one WG (1024 threads, 16 waves) per
// chain. FULL W_hh residency at 1024 threads under the observed 128-VGPR
// allocator behavior:
//   96 weight dwords/thread in VGPRs (384 KB) + 128 KB in LDS = 512 KB = all
//   of W_hh as f16. Working set ~27 regs -> ~123 total <= 128 cap (cap is
//   also the HW requirement: 16 waves/WG = 4 waves/EU).
// Static LDS (the two runs that got the full 128-reg cap were static-LDS).
// Thread t: kg = t>>7 (k-span 64, wave-uniform), hg = t&127.
// Output rows h = hg + 128*i: i=0..2 in VGPRs, i=3 in LDS.
// ---------------------------------------------------------------------------
__global__ __launch_bounds__(1024, 4) void rnn_scan(
    const float* __restrict__ Whh, const float* __restrict__ bhh,
    float* __restrict__ out, float* __restrict__ last) {
  __shared__ uint2 wlds[16 * 1024];       // 128 KB: W rows hg+384
  __shared__ float part[8 * 512];         // 16 KB partials
  __shared__ unsigned short hbuf[512];    // 1 KB h state (f16)

  const int b = blockIdx.x;
  const int t = threadIdx.x;
  const int kg = t >> 7;        // 0..7, wave-uniform (2 waves per kg)
  const int hg = t & 127;
  const int k0 = kg * 64;

  // --- one-time weight load: rows h = hg + 128*i, k in [k0, k0+64) ---
  unsigned int wreg[3][32];
#pragma unroll
  for (int i = 0; i < 3; ++i) {
    const float* wr = Whh + (size_t)(hg + 128 * i) * 512 + k0;
#pragma unroll
    for (int c4 = 0; c4 < 16; ++c4) {
      float4 f = ((const float4*)wr)[c4];
      wreg[i][c4 * 2]     = pack_h2(f.x, f.y);
      wreg[i][c4 * 2 + 1] = pack_h2(f.z, f.w);
    }
  }
  // pin: opaque defs, no remat/sink of the load+convert chain into the loop
#pragma unroll
  for (int i = 0; i < 3; ++i)
#pragma unroll
    for (int d = 0; d < 32; ++d) asm volatile("" : "+v"(wreg[i][d]));

  // --- row-group i=3 into LDS ---
  {
    const float* wr3 = Whh + (size_t)(hg + 384) * 512 + k0;
#pragma unroll
    for (int j2 = 0; j2 < 16; ++j2) {
      float4 f = ((const float4*)wr3)[j2];
      wlds[j2 * 1024 + t] = make_uint2(pack_h2(f.x, f.y), pack_h2(f.z, f.w));
    }
  }
  if (t < 256) ((unsigned int*)hbuf)[t] = 0;  // h_0 = 0

  float* xt_row = out + (size_t)b * SS * HH;
  float xt_cur = 0.f, bh = 0.f;
  if (t < 512) { xt_cur = xt_row[t]; bh = bhh[t]; }
  const uint2* wp = wlds + t;
  const uint4* h4 = (const uint4*)hbuf + kg * 8;
  __syncthreads();

  for (int step = 0; step < SS; ++step) {
    // prefetch next xt (consumed next iteration; hides under dot phase)
    float xt_next = 0.f;
    if (t < 512 && step + 1 < SS) xt_next = xt_row[(size_t)(step + 1) * HH + t];

    // --- dot phase: a[i] over k in [kg*64, kg*64+64), 128 dot2/thread ---
    float a0 = 0.f, a1 = 0.f, a2 = 0.f, a3 = 0.f;
#pragma unroll
    for (int c = 0; c < 8; ++c) {
      uint4 hv = h4[c];                       // wave-uniform -> broadcast
      a0 = dot2a(wreg[0][4 * c + 0], hv.x, a0);
      a0 = dot2a(wreg[0][4 * c + 1], hv.y, a0);
      a0 = dot2a(wreg[0][4 * c + 2], hv.z, a0);
      a0 = dot2a(wreg[0][4 * c + 3], hv.w, a0);
      a1 = dot2a(wreg[1][4 * c + 0], hv.x, a1);
      a1 = dot2a(wreg[1][4 * c + 1], hv.y, a1);
      a1 = dot2a(wreg[1][4 * c + 2], hv.z, a1);
      a1 = dot2a(wreg[1][4 * c + 3], hv.w, a1);
      a2 = dot2a(wreg[2][4 * c + 0], hv.x, a2);
      a2 = dot2a(wreg[2][4 * c + 1], hv.y, a2);
      a2 = dot2a(wreg[2][4 * c + 2], hv.z, a2);
      a2 = dot2a(wreg[2][4 * c + 3], hv.w, a2);
      uint2 wa = wp[(2 * c) * 1024];          // conflict-free b64
      uint2 wb = wp[(2 * c + 1) * 1024];
      a3 = dot2a(wa.x, hv.x, a3);
      a3 = dot2a(wa.y, hv.y, a3);
      a3 = dot2a(wb.x, hv.z, a3);
      a3 = dot2a(wb.y, hv.w, a3);
    }
    // partial store: per wave, 64 consecutive dwords per i -> conflict-free
    part[kg * 512 + hg]       = a0;
    part[kg * 512 + hg + 128] = a1;
    part[kg * 512 + hg + 256] = a2;
    part[kg * 512 + hg + 384] = a3;
    __syncthreads();

    // --- finalize: threads 0..511, h = t ---
    if (t < 512) {
      float y = xt_cur + bh;
#pragma unroll
      for (int g = 0; g < 8; ++g) y += part[g * 512 + t];
      float ht = tanhf(y);
      xt_row[(size_t)step * HH + t] = ht;  // overwrite xt with output h
      hbuf[t] = __builtin_bit_cast(unsigned short, (_Float16)ht);
    }
    xt_cur = xt_next;
    __syncthreads();
  }

  // last = h_{S-1}: re-read the fp32 value just stored (L1/L2-hot)
  if (t < 512) last[(size_t)b * HH + t] = xt_row[(size_t)(SS - 1) * HH + t];
}

extern "C" void kernel_launch(void* const* d_in, const int* in_sizes, int n_in,
                              void* d_out, int out_size, void* d_ws, size_t ws_size,
                              hipStream_t stream) {
  (void)in_sizes; (void)n_in; (void)d_ws; (void)ws_size; (void)out_size;
  const float* x   = (const float*)d_in[0];
  const float* Wih = (const float*)d_in[1];
  const float* bih = (const float*)d_in[2];
  const float* Whh = (const float*)d_in[3];
  const float* bhh = (const float*)d_in[4];
  float* out  = (float*)d_out;
  float* last = out + (size_t)BB * SS * HH;

  // Phase 1: input projection for all timesteps -> d_out (in-place xt buffer)
  xt_gemm<<<dim3(8, 1024), 256, 0, stream>>>(x, Wih, bih, out);

  // Phase 2: 64 sync-free per-batch chains, 145 KB static LDS, 1024 threads
  rnn_scan<<<64, 1024, 0, stream>>>(Whh, bhh, out, last);
}

// Round 8
// 1616.513 us; speedup vs baseline: 1.3180x; 1.0837x over previous
//
#include <hip/hip_runtime.h>

#define BB 64
#define SS 1024
#define HH 512

typedef short short8 __attribute__((ext_vector_type(8)));
typedef float f32x4 __attribute__((ext_vector_type(4)));
typedef _Float16 h2 __attribute__((ext_vector_type(2)));

__device__ inline unsigned short f2bf(float f) {
  unsigned int u = __builtin_bit_cast(unsigned int, f);
  u += 0x7fffu + ((u >> 16) & 1u);   // round-to-nearest-even
  return (unsigned short)(u >> 16);
}

__device__ inline unsigned int pack_h2(float a, float b) {
  unsigned short ua = __builtin_bit_cast(unsigned short, (_Float16)a);
  unsigned short ub = __builtin_bit_cast(unsigned short, (_Float16)b);
  return (unsigned int)ua | ((unsigned int)ub << 16);
}

__device__ inline float dot2a(unsigned int w, unsigned int h, float acc) {
#if __has_builtin(__builtin_amdgcn_fdot2)
  return __builtin_amdgcn_fdot2(__builtin_bit_cast(h2, w),
                                __builtin_bit_cast(h2, h), acc, false);
#else
  h2 a = __builtin_bit_cast(h2, w);
  h2 b = __builtin_bit_cast(h2, h);
  return acc + (float)a[0] * (float)b[0] + (float)a[1] * (float)b[1];
#endif
}

// ---------------------------------------------------------------------------
// Phase 1: xt[m, n] = sum_k x[m,k] * W_ih[n,k] + b_ih[n],  m = b*S + s
// bf16 MFMA 16x16x32, BM=BN=64, BK=32, 256 threads (4 waves, 2x2 wave grid).
// Writes fp32 into d_out[0 : B*S*H]; phase 2 overwrites in place.
// ---------------------------------------------------------------------------
__global__ __launch_bounds__(256) void xt_gemm(
    const float* __restrict__ x, const float* __restrict__ Wih,
    const float* __restrict__ bih, float* __restrict__ out) {
  __shared__ unsigned short As[64][56];
  __shared__ unsigned short Bs[64][56];

  const int bn = blockIdx.x;  // 0..7
  const int bm = blockIdx.y;  // 0..1023
  const int t = threadIdx.x;
  const int wave = t >> 6, lane = t & 63;
  const int wm = wave >> 1, wn = wave & 1;
  const int m_base = bm * 64, n_base = bn * 64;
  const int sr = t >> 2;        // staging row 0..63
  const int sc = (t & 3) * 8;   // staging col chunk 0,8,16,24

  f32x4 acc[2][2] = {};

  for (int k0 = 0; k0 < 512; k0 += 32) {
    __syncthreads();
    {
      const float* p = x + (size_t)(m_base + sr) * 512 + k0 + sc;
      float4 v0 = *(const float4*)p;
      float4 v1 = *(const float4*)(p + 4);
      short8 sa;
      sa[0] = (short)f2bf(v0.x); sa[1] = (short)f2bf(v0.y);
      sa[2] = (short)f2bf(v0.z); sa[3] = (short)f2bf(v0.w);
      sa[4] = (short)f2bf(v1.x); sa[5] = (short)f2bf(v1.y);
      sa[6] = (short)f2bf(v1.z); sa[7] = (short)f2bf(v1.w);
      *(short8*)&As[sr][sc] = sa;

      const float* q = Wih + (size_t)(n_base + sr) * 512 + k0 + sc;
      float4 w0 = *(const float4*)q;
      float4 w1 = *(const float4*)(q + 4);
      short8 sb;
      sb[0] = (short)f2bf(w0.x); sb[1] = (short)f2bf(w0.y);
      sb[2] = (short)f2bf(w0.z); sb[3] = (short)f2bf(w0.w);
      sb[4] = (short)f2bf(w1.x); sb[5] = (short)f2bf(w1.y);
      sb[6] = (short)f2bf(w1.z); sb[7] = (short)f2bf(w1.w);
      *(short8*)&Bs[sr][sc] = sb;
    }
    __syncthreads();

    const int kq = (lane >> 4) * 8;  // k-chunk within BK
    short8 a0 = *(const short8*)&As[wm * 32 + (lane & 15)][kq];
    short8 a1 = *(const short8*)&As[wm * 32 + 16 + (lane & 15)][kq];
    short8 b0 = *(const short8*)&Bs[wn * 32 + (lane & 15)][kq];
    short8 b1 = *(const short8*)&Bs[wn * 32 + 16 + (lane & 15)][kq];
    acc[0][0] = __builtin_amdgcn_mfma_f32_16x16x32_bf16(a0, b0, acc[0][0], 0, 0, 0);
    acc[0][1] = __builtin_amdgcn_mfma_f32_16x16x32_bf16(a0, b1, acc[0][1], 0, 0, 0);
    acc[1][0] = __builtin_amdgcn_mfma_f32_16x16x32_bf16(a1, b0, acc[1][0], 0, 0, 0);
    acc[1][1] = __builtin_amdgcn_mfma_f32_16x16x32_bf16(a1, b1, acc[1][1], 0, 0, 0);
  }

  // C/D layout (m89-verified): col = lane&15 (N), row = (lane>>4)*4 + j (M)
#pragma unroll
  for (int ni = 0; ni < 2; ++ni) {
    const int gcol = n_base + wn * 32 + ni * 16 + (lane & 15);
    const float bv = bih[gcol];
#pragma unroll
    for (int mi = 0; mi < 2; ++mi) {
#pragma unroll
      for (int j = 0; j < 4; ++j) {
        const int grow = m_base + wm * 32 + mi * 16 + (lane >> 4) * 4 + j;
        out[(size_t)grow * 512 + gcol] = acc[mi][ni][j] + bv;
      }
    }
  }
}

// ---------------------------------------------------------------------------
// Phase 2: per-batch sequential scan, one WG (512 threads, 8 waves) per chain.
// KEY CHANGE vs R3/R5: every weight dword is LAUNDERED through a volatile
// v_mov_b32 asm. Volatile asm outputs cannot be rematerialized — the
// backend's only options are register residency or scratch spill (pure
// reload, no cvt/pack re-execution). This targets the observed failure
// mode where the invariant load+convert chain was sunk into the step loop.
// Thread t: kg = t>>6 (k-span 64, wave-uniform), hg = t&63.
// Outputs h = hg + 64*i, i=0..7: i=0..5 in VGPRs, i=6..7 in LDS (128 KB).
// ---------------------------------------------------------------------------
__global__ __launch_bounds__(512, 1) void rnn_scan(
    const float* __restrict__ Whh, const float* __restrict__ bhh,
    float* __restrict__ out, float* __restrict__ last) {
  __shared__ uint4 wlds[16 * 512];        // 128 KB: W rows hg+384, hg+448
  __shared__ float part[8 * 512];         // 16 KB partials
  __shared__ unsigned short hbuf[512];    // 1 KB h state (f16)

  const int b = blockIdx.x;
  const int t = threadIdx.x;
  const int kg = t >> 6;        // 0..7, wave-uniform
  const int hg = t & 63;
  const int k0 = kg * 64;

  // --- one-time weight load: rows h = hg + 64*i, k in [k0, k0+64) ---
  // Each dword laundered: value identity becomes opaque to the optimizer.
  unsigned int wreg[6][32];
#pragma unroll
  for (int i = 0; i < 6; ++i) {
    const float* wr = Whh + (size_t)(hg + 64 * i) * 512 + k0;
#pragma unroll
    for (int c4 = 0; c4 < 16; ++c4) {
      float4 f = ((const float4*)wr)[c4];
      unsigned int lo = pack_h2(f.x, f.y);
      unsigned int hi = pack_h2(f.z, f.w);
      asm volatile("v_mov_b32 %0, %1" : "=v"(wreg[i][c4 * 2])     : "v"(lo));
      asm volatile("v_mov_b32 %0, %1" : "=v"(wreg[i][c4 * 2 + 1]) : "v"(hi));
    }
  }

  // --- rows i=6..7 into LDS ---
#pragma unroll
  for (int i = 6; i < 8; ++i) {
    const float* wr = Whh + (size_t)(hg + 64 * i) * 512 + k0;
#pragma unroll
    for (int c = 0; c < 8; ++c) {
      float4 f0 = ((const float4*)wr)[c * 2];
      float4 f1 = ((const float4*)wr)[c * 2 + 1];
      uint4 v;
      v.x = pack_h2(f0.x, f0.y); v.y = pack_h2(f0.z, f0.w);
      v.z = pack_h2(f1.x, f1.y); v.w = pack_h2(f1.z, f1.w);
      wlds[((i - 6) * 8 + c) * 512 + t] = v;
    }
  }
  if (t < 256) ((unsigned int*)hbuf)[t] = 0;  // h_0 = 0

  float* xt_row = out + (size_t)b * SS * HH;
  float xt_cur = xt_row[t];
  const float bh = bhh[t];
  const uint4* h4 = (const uint4*)hbuf + kg * 8;
  __syncthreads();

  for (int step = 0; step < SS; ++step) {
    // prefetch next xt (consumed next iteration; hides under dot phase)
    float xt_next = 0.f;
    if (step + 1 < SS) xt_next = xt_row[(size_t)(step + 1) * HH + t];

    // --- dot phase: a[i] = sum over k-span of W[hg+64i][k] * h[k] ---
    float a[8] = {0.f, 0.f, 0.f, 0.f, 0.f, 0.f, 0.f, 0.f};
#pragma unroll
    for (int c = 0; c < 8; ++c) {
      uint4 hv = h4[c];                      // broadcast (wave-uniform addr)
      uint4 w6 = wlds[c * 512 + t];          // conflict-free b128
      uint4 w7 = wlds[(8 + c) * 512 + t];
      a[0] = dot2a(wreg[0][4 * c + 0], hv.x, a[0]);
      a[0] = dot2a(wreg[0][4 * c + 1], hv.y, a[0]);
      a[0] = dot2a(wreg[0][4 * c + 2], hv.z, a[0]);
      a[0] = dot2a(wreg[0][4 * c + 3], hv.w, a[0]);
      a[1] = dot2a(wreg[1][4 * c + 0], hv.x, a[1]);
      a[1] = dot2a(wreg[1][4 * c + 1], hv.y, a[1]);
      a[1] = dot2a(wreg[1][4 * c + 2], hv.z, a[1]);
      a[1] = dot2a(wreg[1][4 * c + 3], hv.w, a[1]);
      a[2] = dot2a(wreg[2][4 * c + 0], hv.x, a[2]);
      a[2] = dot2a(wreg[2][4 * c + 1], hv.y, a[2]);
      a[2] = dot2a(wreg[2][4 * c + 2], hv.z, a[2]);
      a[2] = dot2a(wreg[2][4 * c + 3], hv.w, a[2]);
      a[3] = dot2a(wreg[3][4 * c + 0], hv.x, a[3]);
      a[3] = dot2a(wreg[3][4 * c + 1], hv.y, a[3]);
      a[3] = dot2a(wreg[3][4 * c + 2], hv.z, a[3]);
      a[3] = dot2a(wreg[3][4 * c + 3], hv.w, a[3]);
      a[4] = dot2a(wreg[4][4 * c + 0], hv.x, a[4]);
      a[4] = dot2a(wreg[4][4 * c + 1], hv.y, a[4]);
      a[4] = dot2a(wreg[4][4 * c + 2], hv.z, a[4]);
      a[4] = dot2a(wreg[4][4 * c + 3], hv.w, a[4]);
      a[5] = dot2a(wreg[5][4 * c + 0], hv.x, a[5]);
      a[5] = dot2a(wreg[5][4 * c + 1], hv.y, a[5]);
      a[5] = dot2a(wreg[5][4 * c + 2], hv.z, a[5]);
      a[5] = dot2a(wreg[5][4 * c + 3], hv.w, a[5]);
      a[6] = dot2a(w6.x, hv.x, a[6]);
      a[6] = dot2a(w6.y, hv.y, a[6]);
      a[6] = dot2a(w6.z, hv.z, a[6]);
      a[6] = dot2a(w6.w, hv.w, a[6]);
      a[7] = dot2a(w7.x, hv.x, a[7]);
      a[7] = dot2a(w7.y, hv.y, a[7]);
      a[7] = dot2a(w7.z, hv.z, a[7]);
      a[7] = dot2a(w7.w, hv.w, a[7]);
    }
    // partial store: within a wave lanes write consecutive dwords
#pragma unroll
    for (int i = 0; i < 8; ++i) part[kg * 512 + hg + 64 * i] = a[i];
    __syncthreads();

    // --- finalize: all 512 threads, h = t ---
    float y = xt_cur + bh;
#pragma unroll
    for (int g = 0; g < 8; ++g) y += part[g * 512 + t];
    float ht = tanhf(y);
    xt_row[(size_t)step * HH + t] = ht;  // overwrite xt with output h
    hbuf[t] = __builtin_bit_cast(unsigned short, (_Float16)ht);
    xt_cur = xt_next;
    __syncthreads();
  }

  // last = h_{S-1}: re-read the fp32 value just stored (L1/L2-hot)
  last[(size_t)b * HH + t] = xt_row[(size_t)(SS - 1) * HH + t];
}

extern "C" void kernel_launch(void* const* d_in, const int* in_sizes, int n_in,
                              void* d_out, int out_size, void* d_ws, size_t ws_size,
                              hipStream_t stream) {
  (void)in_sizes; (void)n_in; (void)d_ws; (void)ws_size; (void)out_size;
  const float* x   = (const float*)d_in[0];
  const float* Wih = (const float*)d_in[1];
  const float* bih = (const float*)d_in[2];
  const float* Whh = (const float*)d_in[3];
  const float* bhh = (const float*)d_in[4];
  float* out  = (float*)d_out;
  float* last = out + (size_t)BB * SS * HH;

  // Phase 1: input projection for all timesteps -> d_out (in-place xt buffer)
  xt_gemm<<<dim3(8, 1024), 256, 0, stream>>>(x, Wih, bih, out);

  // Phase 2: 64 sync-free per-batch chains, 145 KB static LDS each
  rnn_scan<<<64, 512, 0, stream>>>(Whh, bhh, out, last);
}